// Round 23
// baseline (213.356 us; speedup 1.0000x reference)
//
#include <hip/hip_runtime.h>
#include <hip/hip_bf16.h>
#include <float.h>

#define BSZ 16384
#define NCODES 1024
#define QD 2048
#define NCHUNK 64   // BSZ / 256
#define NCOLG 32    // 16 col-blocks x 2 wc-waves (pre path); fallback uses 16

typedef _Float16 f16x8 __attribute__((ext_vector_type(8)));
typedef _Float16 f16x4 __attribute__((ext_vector_type(4)));
typedef float f32x4 __attribute__((ext_vector_type(4)));

static __device__ __forceinline__ float one_minus_decay() { return (float)(1.0 - 0.99); }

static __device__ __forceinline__ void async_copy16(const void* src, void* lds) {
    __builtin_amdgcn_global_load_lds((const __attribute__((address_space(1))) void*)src,
                                     (__attribute__((address_space(3))) void*)lds, 16, 0, 0);
}

// ---------------- K1a: unified prep -- EVERY row (ctx then q) -> fp16 hi + norm ----
__global__ void k_prep_all(const float* __restrict__ ctx, const float* __restrict__ q,
                           _Float16* __restrict__ gh, float* __restrict__ gsq,
                           _Float16* __restrict__ qh, float* __restrict__ qsq) {
    __shared__ float red[4];
    int tid = threadIdx.x;
    const float* src; _Float16* dh; float* nrm;
    if (blockIdx.x < NCODES) {
        size_t n = blockIdx.x;
        src = ctx + n * QD; dh = gh + n * QD; nrm = gsq + n;
    } else {
        size_t b = blockIdx.x - NCODES;
        src = q + b * QD; dh = qh + b * QD; nrm = qsq + b;
    }
    int c = tid * 8;
    float4 t0 = *(const float4*)(src + c);
    float4 t1 = *(const float4*)(src + c + 4);
    float s = t0.x * t0.x + t0.y * t0.y + t0.z * t0.z + t0.w * t0.w
            + t1.x * t1.x + t1.y * t1.y + t1.z * t1.z + t1.w * t1.w;
    f16x8 h;
    h[0] = (_Float16)t0.x; h[1] = (_Float16)t0.y;
    h[2] = (_Float16)t0.z; h[3] = (_Float16)t0.w;
    h[4] = (_Float16)t1.x; h[5] = (_Float16)t1.y;
    h[6] = (_Float16)t1.z; h[7] = (_Float16)t1.w;
    *(f16x8*)(dh + c) = h;
    for (int off = 32; off > 0; off >>= 1) s += __shfl_down(s, off);
    if ((tid & 63) == 0) red[tid >> 6] = s;
    __syncthreads();
    if (tid == 0) *nrm = red[0] + red[1] + red[2] + red[3];
}

// ---------------- K1b: fallback prep (if ws too small for qh) ----------------
__global__ void k_prep_r17(const float* __restrict__ ctx, const float* __restrict__ q,
                           _Float16* __restrict__ gh, float* __restrict__ gsq,
                           float* __restrict__ qsq) {
    int tid = threadIdx.x;
    if (blockIdx.x < NCODES) {
        __shared__ float red[4];
        int n = blockIdx.x;
        float s = 0.f;
#pragma unroll
        for (int i = 0; i < 2; ++i) {
            int c = (tid + i * 256) * 4;
            float4 t = *(const float4*)(ctx + (size_t)n * QD + c);
            f16x4 h;
            h[0] = (_Float16)t.x; h[1] = (_Float16)t.y;
            h[2] = (_Float16)t.z; h[3] = (_Float16)t.w;
            *(f16x4*)(gh + (size_t)n * QD + c) = h;
            s += t.x * t.x + t.y * t.y + t.z * t.z + t.w * t.w;
        }
        for (int off = 32; off > 0; off >>= 1) s += __shfl_down(s, off);
        if ((tid & 63) == 0) red[tid >> 6] = s;
        __syncthreads();
        if (tid == 0) gsq[n] = red[0] + red[1] + red[2] + red[3];
    } else {
        int w = tid >> 6, lane = tid & 63;
        int b = (blockIdx.x - NCODES) * 4 + w;
        const float4* row = (const float4*)(q + (size_t)b * QD);
        float s = 0.f;
#pragma unroll
        for (int i = 0; i < 8; ++i) {
            float4 v = row[lane + i * 64];
            s += v.x * v.x + v.y * v.y + v.z * v.z + v.w * v.w;
        }
        for (int off = 32; off > 0; off >>= 1) s += __shfl_down(s, off);
        if (lane == 0) qsq[b] = s;
    }
}

// ---------------- K2a: 1-term fp16 GEMM, 128x64 tile, counted-vmcnt pipeline --------
// r20's pipeline (measured best structure) with HALF the column width to raise
// occupancy: tile 128 rows x 64 cols, 4 waves of 64x32 (acc 32 AGPR, combined regs
// ~112-120 < 128-bracket; LDS 48KB -> 3 blocks/CU vs 2). Grid 2048 blocks = more
// independent blocks hiding each other's latency (r11 lesson). Same BK=64, same
// swizzle, same per-fragment K-order -> distances BIT-IDENTICAL -> absmax must
// stay 0.05090332. Per tile/wave: 6 gload_lds (4 A + 2 B), vmcnt(6).
// (Ledger -- do NOT re-try: BK=32 2-barrier, dbuf-__syncthreads, 32x32 MFMA,
//  qsq-fusion, stage-B-first, 512-thr, A-in-reg stride-4KB.)
__launch_bounds__(256)
__global__ void k_dist_pre(const _Float16* __restrict__ qh, const _Float16* __restrict__ gh,
                           const float* __restrict__ gsq,
                           float* __restrict__ pval, int* __restrict__ pidx) {
    __shared__ _Float16 ah[2][128][64];   // 32 KB
    __shared__ _Float16 bh[2][64][64];    // 16 KB

    const int tid = threadIdx.x;
    const int lane = tid & 63, wid = tid >> 6;
    const int wr = wid >> 1, wc = wid & 1;
    // XCD-chunked mapping: 16 col-blocks of one row-tile dispatch-adjacent per XCD.
    const int n0 = blockIdx.x;
    const int xcd = n0 & 7, j = n0 >> 3;          // j in 0..255
    const int col = j & 15, rowt = xcd * 16 + (j >> 4);
    const int colBase = col * 64, rowBase = rowt * 128;
    const int fr = lane & 15, kg = lane >> 4;

    const int srow = lane >> 3;
    const int gran = (lane & 7) ^ (lane >> 3);

    f32x4 acc[4][2];
#pragma unroll
    for (int m = 0; m < 4; ++m)
#pragma unroll
        for (int n = 0; n < 2; ++n) acc[m][n] = (f32x4)0.f;

#define STAGE_TILE(KB, BUF)                                                           \
    {                                                                                 \
        _Pragma("unroll")                                                             \
        for (int i_ = 0; i_ < 4; ++i_) {                                              \
            int g_ = wid * 4 + i_;                                                    \
            size_t ro_ = (size_t)(rowBase + g_ * 8 + srow) * QD + (KB) + gran * 8;    \
            async_copy16(qh + ro_, &ah[BUF][g_ * 8][0]);                              \
        }                                                                             \
        _Pragma("unroll")                                                             \
        for (int i_ = 0; i_ < 2; ++i_) {                                              \
            int g_ = wid * 2 + i_;                                                    \
            size_t co_ = (size_t)(colBase + g_ * 8 + srow) * QD + (KB) + gran * 8;    \
            async_copy16(gh + co_, &bh[BUF][g_ * 8][0]);                              \
        }                                                                             \
    }

#define COMPUTE_TILE(BUF)                                                             \
    {                                                                                 \
        const char* ahB_ = (const char*)&ah[BUF][0][0];                               \
        const char* bhB_ = (const char*)&bh[BUF][0][0];                               \
        _Pragma("unroll")                                                             \
        for (int h_ = 0; h_ < 2; ++h_) {                                              \
            f16x8 a_h[4], b_h[2];                                                     \
            _Pragma("unroll")                                                         \
            for (int m_ = 0; m_ < 4; ++m_) {                                          \
                int ar_ = wr * 64 + m_ * 16 + fr;                                     \
                int off_ = ar_ * 128 + ((h_ * 64 + kg * 16) ^ ((ar_ & 7) << 4));      \
                a_h[m_] = *(const f16x8*)(ahB_ + off_);                               \
            }                                                                         \
            _Pragma("unroll")                                                         \
            for (int n_ = 0; n_ < 2; ++n_) {                                          \
                int br_ = wc * 32 + n_ * 16 + fr;                                     \
                int off_ = br_ * 128 + ((h_ * 64 + kg * 16) ^ ((br_ & 7) << 4));      \
                b_h[n_] = *(const f16x8*)(bhB_ + off_);                               \
            }                                                                         \
            _Pragma("unroll")                                                         \
            for (int m_ = 0; m_ < 4; ++m_)                                            \
                _Pragma("unroll")                                                     \
                for (int n_ = 0; n_ < 2; ++n_)                                        \
                    acc[m_][n_] = __builtin_amdgcn_mfma_f32_16x16x32_f16(             \
                        a_h[m_], b_h[n_], acc[m_][n_], 0, 0, 0);                      \
        }                                                                             \
    }

    STAGE_TILE(0, 0);
    STAGE_TILE(64, 1);

    for (int t = 0; t < 31; ++t) {
        asm volatile("s_waitcnt vmcnt(6)" ::: "memory");   // tile-t's 6 loads landed
        __builtin_amdgcn_s_barrier();
        COMPUTE_TILE(t & 1);
        __builtin_amdgcn_s_barrier();
        if (t < 30) STAGE_TILE((t + 2) * 64, t & 1);
    }
    asm volatile("s_waitcnt vmcnt(0)" ::: "memory");
    __builtin_amdgcn_s_barrier();
    COMPUTE_TILE(1);

#undef STAGE_TILE
#undef COMPUTE_TILE

    // epilogue: d = gsq - 2*dot; per-row argmin (first-occurrence ties)
    float mv[4][4]; int mi[4][4];
#pragma unroll
    for (int m = 0; m < 4; ++m)
#pragma unroll
        for (int r = 0; r < 4; ++r) { mv[m][r] = FLT_MAX; mi[m][r] = 0x7fffffff; }
#pragma unroll
    for (int n = 0; n < 2; ++n) {
        int c = colBase + wc * 32 + n * 16 + fr;
        float gq = gsq[c];
#pragma unroll
        for (int m = 0; m < 4; ++m)
#pragma unroll
            for (int r = 0; r < 4; ++r) {
                float d = gq - 2.0f * acc[m][n][r];
                if (d < mv[m][r]) { mv[m][r] = d; mi[m][r] = c; }
            }
    }
#pragma unroll
    for (int off = 1; off < 16; off <<= 1) {
#pragma unroll
        for (int m = 0; m < 4; ++m)
#pragma unroll
            for (int r = 0; r < 4; ++r) {
                float ov = __shfl_xor(mv[m][r], off);
                int   oi = __shfl_xor(mi[m][r], off);
                if (ov < mv[m][r] || (ov == mv[m][r] && oi < mi[m][r])) { mv[m][r] = ov; mi[m][r] = oi; }
            }
    }
    if (fr == 0) {
        const size_t slot = (size_t)(col * 2 + wc) * BSZ;   // 32 slots
#pragma unroll
        for (int m = 0; m < 4; ++m)
#pragma unroll
            for (int r = 0; r < 4; ++r) {
                int grow = rowBase + wr * 64 + m * 16 + kg * 4 + r;
                pval[slot + grow] = mv[m][r];
                pidx[slot + grow] = mi[m][r];
            }
    }
}

// ---------------- K2b: fallback GEMM (in-loop q cvt, r17 -- 16 slots) ---------------
__launch_bounds__(256)
__global__ void k_dist_r17(const float* __restrict__ q, const _Float16* __restrict__ gh,
                           const float* __restrict__ gsq,
                           float* __restrict__ pval, int* __restrict__ pidx) {
    __shared__ _Float16 ah[128][64];
    __shared__ _Float16 bh[128][64];

    const int tid = threadIdx.x;
    const int lane = tid & 63, wid = tid >> 6;
    const int wr = wid >> 1, wc = wid & 1;
    const int n0 = blockIdx.x;
    const int xcd = n0 & 7, j = n0 >> 3;
    const int col = j & 7, rowt = xcd * 16 + (j >> 3);
    const int colBase = col * 128, rowBase = rowt * 128;
    const int fr = lane & 15, kg = lane >> 4;

    char* ahB = (char*)&ah[0][0];
    const char* bhB = (const char*)&bh[0][0];

    f32x4 acc[4][4];
#pragma unroll
    for (int m = 0; m < 4; ++m)
#pragma unroll
        for (int n = 0; n < 4; ++n) acc[m][n] = (f32x4)0.f;

    for (int kb = 0; kb < QD; kb += 64) {
        __syncthreads();
#pragma unroll
        for (int s = 0; s < 8; ++s) {
            int f = s * 256 + tid;
            int row = f >> 4, k4 = (f & 15) * 4;
            float4 t = *(const float4*)(q + (size_t)(rowBase + row) * QD + kb + k4);
            f16x4 h;
            h[0] = (_Float16)t.x; h[1] = (_Float16)t.y;
            h[2] = (_Float16)t.z; h[3] = (_Float16)t.w;
            int byt = (row * 128 + k4 * 2) ^ ((row & 7) << 4);
            *(f16x4*)(ahB + byt) = h;
        }
#pragma unroll
        for (int i = 0; i < 4; ++i) {
            int g = wid * 4 + i;
            int row = g * 8 + (lane >> 3);
            int gran = (lane & 7) ^ (lane >> 3);
            size_t goff = (size_t)(colBase + row) * QD + kb + gran * 8;
            async_copy16(gh + goff, &bh[g * 8][0]);
        }
        __syncthreads();

#pragma unroll
        for (int h = 0; h < 2; ++h) {
            f16x8 a_h[4], b_h[4];
#pragma unroll
            for (int m = 0; m < 4; ++m) {
                int ar = wr * 64 + m * 16 + fr;
                int off = ar * 128 + ((h * 64 + kg * 16) ^ ((ar & 7) << 4));
                a_h[m] = *(const f16x8*)(ahB + off);
            }
#pragma unroll
            for (int n = 0; n < 4; ++n) {
                int br = wc * 64 + n * 16 + fr;
                int off = br * 128 + ((h * 64 + kg * 16) ^ ((br & 7) << 4));
                b_h[n] = *(const f16x8*)(bhB + off);
            }
#pragma unroll
            for (int m = 0; m < 4; ++m)
#pragma unroll
                for (int n = 0; n < 4; ++n)
                    acc[m][n] = __builtin_amdgcn_mfma_f32_16x16x32_f16(a_h[m], b_h[n], acc[m][n], 0, 0, 0);
        }
    }

    float mv[4][4]; int mi[4][4];
#pragma unroll
    for (int m = 0; m < 4; ++m)
#pragma unroll
        for (int r = 0; r < 4; ++r) { mv[m][r] = FLT_MAX; mi[m][r] = 0x7fffffff; }
#pragma unroll
    for (int n = 0; n < 4; ++n) {
        int c = colBase + wc * 64 + n * 16 + fr;
        float gq = gsq[c];
#pragma unroll
        for (int m = 0; m < 4; ++m)
#pragma unroll
            for (int r = 0; r < 4; ++r) {
                float d = gq - 2.0f * acc[m][n][r];
                if (d < mv[m][r]) { mv[m][r] = d; mi[m][r] = c; }
            }
    }
#pragma unroll
    for (int off = 1; off < 16; off <<= 1) {
#pragma unroll
        for (int m = 0; m < 4; ++m)
#pragma unroll
            for (int r = 0; r < 4; ++r) {
                float ov = __shfl_xor(mv[m][r], off);
                int   oi = __shfl_xor(mi[m][r], off);
                if (ov < mv[m][r] || (ov == mv[m][r] && oi < mi[m][r])) { mv[m][r] = ov; mi[m][r] = oi; }
            }
    }
    if (fr == 0) {
        const size_t slot = (size_t)(col * 2 + wc) * BSZ;   // 16 slots
#pragma unroll
        for (int m = 0; m < 4; ++m)
#pragma unroll
            for (int r = 0; r < 4; ++r) {
                int grow = rowBase + wr * 64 + m * 16 + kg * 4 + r;
                pval[slot + grow] = mv[m][r];
                pidx[slot + grow] = mi[m][r];
            }
    }
}

// ---------------- K3: merge nslots partials -> argmin + fused qld + chunk-hist ------
__global__ void k_merge(const float* __restrict__ pval, const int* __restrict__ pidx,
                        const float* __restrict__ qsq, int nslots,
                        int* __restrict__ idx_out, float* __restrict__ qld,
                        int* __restrict__ chunkhist) {
    __shared__ int h[NCODES];
    int c = blockIdx.x, tid = threadIdx.x;
    int b = c * 256 + tid;
#pragma unroll
    for (int s = 0; s < 4; ++s) h[tid + s * 256] = 0;
    float bv = pval[b]; int bi = pidx[b];
    for (int y = 1; y < nslots; ++y) {
        float v = pval[(size_t)y * BSZ + b]; int ii = pidx[(size_t)y * BSZ + b];
        if (v < bv || (v == bv && ii < bi)) { bv = v; bi = ii; }
    }
    idx_out[b] = bi;
    qld[b] = (qsq[b] + bv) * (1.0f / (float)QD);
    __syncthreads();
    atomicAdd(&h[bi], 1);
    __syncthreads();
#pragma unroll
    for (int s = 0; s < 4; ++s) chunkhist[c * NCODES + tid + s * 256] = h[tid + s * 256];
}

// ---------------- K4: scan (counting sort) + fused ec ----------------
__global__ void k_scan(const int* __restrict__ chunkhist, int* __restrict__ base,
                       int* __restrict__ counts, int* __restrict__ offsets,
                       const float* __restrict__ ema_count, float* __restrict__ ec_out) {
    __shared__ int s[NCODES];
    __shared__ float e2[NCODES];
    int code = threadIdx.x;  // 1024 threads
    int run = 0;
    for (int c = 0; c < NCHUNK; ++c) {
        base[c * NCODES + code] = run;
        run += chunkhist[c * NCODES + code];
    }
    counts[code] = run;
    s[code] = run; __syncthreads();
    for (int off = 1; off < NCODES; off <<= 1) {
        int v = (code >= off) ? s[code - off] : 0;
        __syncthreads();
        s[code] += v; __syncthreads();
    }
    offsets[code] = s[code] - run;
    float er = 0.99f * ema_count[code] + one_minus_decay() * (float)run;
    e2[code] = er; __syncthreads();
    for (int off = 512; off > 0; off >>= 1) {
        if (code < off) e2[code] += e2[code + off];
        __syncthreads();
    }
    float n = e2[0];
    ec_out[code] = (er + 1e-5f) / (n + (float)(2048.0 * 1e-5)) * n;
}

__global__ void k_fill(const int* __restrict__ idx, const int* __restrict__ base,
                       const int* __restrict__ offsets, int* __restrict__ list) {
    __shared__ int sidx[256];
    int c = blockIdx.x, tid = threadIdx.x;
    int b = c * 256 + tid;
    int n = idx[b];
    sidx[tid] = n; __syncthreads();
    int rank = 0;
    for (int j = 0; j < tid; ++j) rank += (sidx[j] == n);
    list[offsets[n] + base[c * NCODES + n] + rank] = b;
}

// ---------------- K6a: q_hat segment-sum (fp16 qh) + FUSED finalize ----------------
__global__ void k_qhat_fin_h(const _Float16* __restrict__ qh, const int* __restrict__ counts,
                             const int* __restrict__ offsets, const int* __restrict__ list,
                             const float* __restrict__ ema_dw, const float* __restrict__ ec,
                             float* __restrict__ edw_out, float* __restrict__ ctxnew_out,
                             float* __restrict__ outctx_out) {
    int n = blockIdx.x;
    int col = blockIdx.y * 256 + threadIdx.x;
    int cnt = counts[n];
    const int* lp = list + offsets[n];
    float a0 = 0.f, a1 = 0.f, a2 = 0.f, a3 = 0.f, a4 = 0.f, a5 = 0.f, a6 = 0.f, a7 = 0.f;
    int i = 0;
    for (; i + 8 <= cnt; i += 8) {
        int b0 = lp[i], b1 = lp[i + 1], b2 = lp[i + 2], b3 = lp[i + 3];
        int b4 = lp[i + 4], b5 = lp[i + 5], b6 = lp[i + 6], b7 = lp[i + 7];
        a0 += (float)qh[(size_t)b0 * QD + col]; a1 += (float)qh[(size_t)b1 * QD + col];
        a2 += (float)qh[(size_t)b2 * QD + col]; a3 += (float)qh[(size_t)b3 * QD + col];
        a4 += (float)qh[(size_t)b4 * QD + col]; a5 += (float)qh[(size_t)b5 * QD + col];
        a6 += (float)qh[(size_t)b6 * QD + col]; a7 += (float)qh[(size_t)b7 * QD + col];
    }
    for (; i < cnt; ++i) a0 += (float)qh[(size_t)lp[i] * QD + col];
    float r = ((a0 + a1) + (a2 + a3)) + ((a4 + a5) + (a6 + a7));
    size_t o = (size_t)n * QD + col;
    float ed = 0.99f * ema_dw[o] + one_minus_decay() * r;
    float cn = ed / ec[n];
    edw_out[o] = ed;
    ctxnew_out[o] = cn;
    outctx_out[o] = cn;
}

// ---------------- K6b: fallback (fp32 q) + fused finalize ----------------
__global__ void k_qhat_fin_f(const float* __restrict__ q, const int* __restrict__ counts,
                             const int* __restrict__ offsets, const int* __restrict__ list,
                             const float* __restrict__ ema_dw, const float* __restrict__ ec,
                             float* __restrict__ edw_out, float* __restrict__ ctxnew_out,
                             float* __restrict__ outctx_out) {
    int n = blockIdx.x;
    int col = blockIdx.y * 256 + threadIdx.x;
    int cnt = counts[n];
    const int* lp = list + offsets[n];
    float a0 = 0.f, a1 = 0.f, a2 = 0.f, a3 = 0.f, a4 = 0.f, a5 = 0.f, a6 = 0.f, a7 = 0.f;
    int i = 0;
    for (; i + 8 <= cnt; i += 8) {
        int b0 = lp[i], b1 = lp[i + 1], b2 = lp[i + 2], b3 = lp[i + 3];
        int b4 = lp[i + 4], b5 = lp[i + 5], b6 = lp[i + 6], b7 = lp[i + 7];
        a0 += q[(size_t)b0 * QD + col]; a1 += q[(size_t)b1 * QD + col];
        a2 += q[(size_t)b2 * QD + col]; a3 += q[(size_t)b3 * QD + col];
        a4 += q[(size_t)b4 * QD + col]; a5 += q[(size_t)b5 * QD + col];
        a6 += q[(size_t)b6 * QD + col]; a7 += q[(size_t)b7 * QD + col];
    }
    for (; i < cnt; ++i) a0 += q[(size_t)lp[i] * QD + col];
    float r = ((a0 + a1) + (a2 + a3)) + ((a4 + a5) + (a6 + a7));
    size_t o = (size_t)n * QD + col;
    float ed = 0.99f * ema_dw[o] + one_minus_decay() * r;
    float cn = ed / ec[n];
    edw_out[o] = ed;
    ctxnew_out[o] = cn;
    outctx_out[o] = cn;
}

extern "C" void kernel_launch(void* const* d_in, const int* in_sizes, int n_in,
                              void* d_out, int out_size, void* d_ws, size_t ws_size,
                              hipStream_t stream) {
    const float* q         = (const float*)d_in[0];
    const float* ctx       = (const float*)d_in[1];
    const float* ema_count = (const float*)d_in[2];
    const float* ema_dw    = (const float*)d_in[3];

    float* out = (float*)d_out;
    float* o_qld    = out;                              // 16384
    float* o_outctx = out + BSZ;                        // 2097152
    float* o_ec     = o_outctx + (size_t)NCODES * QD;   // 1024
    float* o_edw    = o_ec + NCODES;                    // 2097152
    float* o_ctxnew = o_edw + (size_t)NCODES * QD;      // 2097152

    char* w = (char*)d_ws;
    float* ws_gsq   = (float*)w;                        // 1024 f
    int* ws_idx     = (int*)(w + 4096);                 // 16384 i
    int* ws_counts  = (int*)(w + 4096 + 65536);         // 1024 i
    int* ws_offsets = ws_counts + NCODES;               // 1024 i
    int* ws_list    = ws_offsets + NCODES;              // 16384 i

    // qh pre-split scratch (64 MB) at ws + 1MB, if available
    const size_t presplit_need = (size_t)1048576 + (size_t)BSZ * QD * sizeof(_Float16);
    const bool use_pre = (ws_size >= presplit_need);
    _Float16* qh = (_Float16*)(w + 1048576);

    // scratch carved from not-yet-written d_out regions:
    _Float16* gh = (_Float16*)o_ctxnew;                 // 4MB (dead after k_dist)
    float* pval  = o_edw;                               // 2MB (dead after k_merge)
    int*   pidx  = (int*)(o_edw + (size_t)NCOLG * BSZ); // 2MB
    float* qsq   = o_edw + (size_t)2 * NCOLG * BSZ;     // 64KB (dead after k_merge)
    int* chunkhist = (int*)o_outctx;                    // 256KB (dead after k_scan)
    int* basep     = chunkhist + NCHUNK * NCODES;       // 256KB (dead after k_fill)

    if (use_pre) {
        k_prep_all<<<NCODES + BSZ, 256, 0, stream>>>(ctx, q, gh, ws_gsq, qh, qsq);
        k_dist_pre<<<2048, 256, 0, stream>>>(qh, gh, ws_gsq, pval, pidx);
        k_merge   <<<NCHUNK, 256, 0, stream>>>(pval, pidx, qsq, 32, ws_idx, o_qld, chunkhist);
    } else {
        k_prep_r17<<<NCODES + BSZ / 4, 256, 0, stream>>>(ctx, q, gh, ws_gsq, qsq);
        k_dist_r17<<<1024, 256, 0, stream>>>(q, gh, ws_gsq, pval, pidx);
        k_merge   <<<NCHUNK, 256, 0, stream>>>(pval, pidx, qsq, 16, ws_idx, o_qld, chunkhist);
    }
    k_scan  <<<1, 1024, 0, stream>>>(chunkhist, basep, ws_counts, ws_offsets, ema_count, o_ec);
    k_fill  <<<NCHUNK, 256, 0, stream>>>(ws_idx, basep, ws_offsets, ws_list);
    if (use_pre) {
        k_qhat_fin_h<<<dim3(NCODES, 8), 256, 0, stream>>>(qh, ws_counts, ws_offsets, ws_list,
                                                          ema_dw, o_ec, o_edw, o_ctxnew, o_outctx);
    } else {
        k_qhat_fin_f<<<dim3(NCODES, 8), 256, 0, stream>>>(q, ws_counts, ws_offsets, ws_list,
                                                          ema_dw, o_ec, o_edw, o_ctxnew, o_outctx);
    }
}

// Round 24
// 191.979 us; speedup vs baseline: 1.1113x; 1.1113x over previous
//
#include <hip/hip_runtime.h>
#include <hip/hip_bf16.h>
#include <float.h>

#define BSZ 16384
#define NCODES 1024
#define QD 2048
#define NCHUNK 64   // BSZ / 256
#define NCOLG 16    // 8 col-blocks x 2 wc-waves

typedef _Float16 f16x8 __attribute__((ext_vector_type(8)));
typedef _Float16 f16x4 __attribute__((ext_vector_type(4)));
typedef float f32x4 __attribute__((ext_vector_type(4)));

static __device__ __forceinline__ float one_minus_decay() { return (float)(1.0 - 0.99); }

static __device__ __forceinline__ void async_copy16(const void* src, void* lds) {
    __builtin_amdgcn_global_load_lds((const __attribute__((address_space(1))) void*)src,
                                     (__attribute__((address_space(3))) void*)lds, 16, 0, 0);
}

// ---------------- K1a: unified prep -- EVERY row (ctx then q) -> fp16 hi + norm ----
__global__ void k_prep_all(const float* __restrict__ ctx, const float* __restrict__ q,
                           _Float16* __restrict__ gh, float* __restrict__ gsq,
                           _Float16* __restrict__ qh, float* __restrict__ qsq) {
    __shared__ float red[4];
    int tid = threadIdx.x;
    const float* src; _Float16* dh; float* nrm;
    if (blockIdx.x < NCODES) {
        size_t n = blockIdx.x;
        src = ctx + n * QD; dh = gh + n * QD; nrm = gsq + n;
    } else {
        size_t b = blockIdx.x - NCODES;
        src = q + b * QD; dh = qh + b * QD; nrm = qsq + b;
    }
    int c = tid * 8;
    float4 t0 = *(const float4*)(src + c);
    float4 t1 = *(const float4*)(src + c + 4);
    float s = t0.x * t0.x + t0.y * t0.y + t0.z * t0.z + t0.w * t0.w
            + t1.x * t1.x + t1.y * t1.y + t1.z * t1.z + t1.w * t1.w;
    f16x8 h;
    h[0] = (_Float16)t0.x; h[1] = (_Float16)t0.y;
    h[2] = (_Float16)t0.z; h[3] = (_Float16)t0.w;
    h[4] = (_Float16)t1.x; h[5] = (_Float16)t1.y;
    h[6] = (_Float16)t1.z; h[7] = (_Float16)t1.w;
    *(f16x8*)(dh + c) = h;
    for (int off = 32; off > 0; off >>= 1) s += __shfl_down(s, off);
    if ((tid & 63) == 0) red[tid >> 6] = s;
    __syncthreads();
    if (tid == 0) *nrm = red[0] + red[1] + red[2] + red[3];
}

// ---------------- K1b: fallback prep (if ws too small for qh) ----------------
__global__ void k_prep_r17(const float* __restrict__ ctx, const float* __restrict__ q,
                           _Float16* __restrict__ gh, float* __restrict__ gsq,
                           float* __restrict__ qsq) {
    int tid = threadIdx.x;
    if (blockIdx.x < NCODES) {
        __shared__ float red[4];
        int n = blockIdx.x;
        float s = 0.f;
#pragma unroll
        for (int i = 0; i < 2; ++i) {
            int c = (tid + i * 256) * 4;
            float4 t = *(const float4*)(ctx + (size_t)n * QD + c);
            f16x4 h;
            h[0] = (_Float16)t.x; h[1] = (_Float16)t.y;
            h[2] = (_Float16)t.z; h[3] = (_Float16)t.w;
            *(f16x4*)(gh + (size_t)n * QD + c) = h;
            s += t.x * t.x + t.y * t.y + t.z * t.z + t.w * t.w;
        }
        for (int off = 32; off > 0; off >>= 1) s += __shfl_down(s, off);
        if ((tid & 63) == 0) red[tid >> 6] = s;
        __syncthreads();
        if (tid == 0) gsq[n] = red[0] + red[1] + red[2] + red[3];
    } else {
        int w = tid >> 6, lane = tid & 63;
        int b = (blockIdx.x - NCODES) * 4 + w;
        const float4* row = (const float4*)(q + (size_t)b * QD);
        float s = 0.f;
#pragma unroll
        for (int i = 0; i < 8; ++i) {
            float4 v = row[lane + i * 64];
            s += v.x * v.x + v.y * v.y + v.z * v.z + v.w * v.w;
        }
        for (int off = 32; off > 0; off >>= 1) s += __shfl_down(s, off);
        if (lane == 0) qsq[b] = s;
    }
}

// ---------------- K2a: 1-term fp16 GEMM, counted-vmcnt pipeline (r20/r22 -- BEST) ---
// MEASURED OPTIMUM of this structure from both sides. Ledger (do NOT re-try):
// BK=32 2-barrier (242), dbuf-__syncthreads (268), 32x32 MFMA (295), qsq-fusion
// (259/264), stage-B-first (264), 512-thr (320), A-in-reg stride-4KB (179),
// 128x64 narrow tile (118: halves MFMA/barrier, 2x A-restage). Latency-bound at
// register-pinned 2 blocks/CU; all pipes <=30%.
__launch_bounds__(256)
__global__ void k_dist_pre(const _Float16* __restrict__ qh, const _Float16* __restrict__ gh,
                           const float* __restrict__ gsq,
                           float* __restrict__ pval, int* __restrict__ pidx) {
    __shared__ _Float16 ah[2][128][64];
    __shared__ _Float16 bh[2][128][64];

    const int tid = threadIdx.x;
    const int lane = tid & 63, wid = tid >> 6;
    const int wr = wid >> 1, wc = wid & 1;
    const int n0 = blockIdx.x;
    const int xcd = n0 & 7, j = n0 >> 3;
    const int col = j & 7, rowt = xcd * 16 + (j >> 3);
    const int colBase = col * 128, rowBase = rowt * 128;
    const int fr = lane & 15, kg = lane >> 4;

    const int srow = lane >> 3;
    const int gran = (lane & 7) ^ (lane >> 3);

    f32x4 acc[4][4];
#pragma unroll
    for (int m = 0; m < 4; ++m)
#pragma unroll
        for (int n = 0; n < 4; ++n) acc[m][n] = (f32x4)0.f;

#define STAGE_TILE(KB, BUF)                                                           \
    {                                                                                 \
        _Pragma("unroll")                                                             \
        for (int i_ = 0; i_ < 4; ++i_) {                                              \
            int g_ = wid * 4 + i_;                                                    \
            size_t ro_ = (size_t)(rowBase + g_ * 8 + srow) * QD + (KB) + gran * 8;    \
            size_t co_ = (size_t)(colBase + g_ * 8 + srow) * QD + (KB) + gran * 8;    \
            async_copy16(qh + ro_, &ah[BUF][g_ * 8][0]);                              \
            async_copy16(gh + co_, &bh[BUF][g_ * 8][0]);                              \
        }                                                                             \
    }

#define COMPUTE_TILE(BUF)                                                             \
    {                                                                                 \
        const char* ahB_ = (const char*)&ah[BUF][0][0];                               \
        const char* bhB_ = (const char*)&bh[BUF][0][0];                               \
        _Pragma("unroll")                                                             \
        for (int h_ = 0; h_ < 2; ++h_) {                                              \
            f16x8 a_h[4], b_h[4];                                                     \
            _Pragma("unroll")                                                         \
            for (int m_ = 0; m_ < 4; ++m_) {                                          \
                int ar_ = wr * 64 + m_ * 16 + fr;                                     \
                int off_ = ar_ * 128 + ((h_ * 64 + kg * 16) ^ ((ar_ & 7) << 4));      \
                a_h[m_] = *(const f16x8*)(ahB_ + off_);                               \
            }                                                                         \
            _Pragma("unroll")                                                         \
            for (int n_ = 0; n_ < 4; ++n_) {                                          \
                int br_ = wc * 64 + n_ * 16 + fr;                                     \
                int off_ = br_ * 128 + ((h_ * 64 + kg * 16) ^ ((br_ & 7) << 4));      \
                b_h[n_] = *(const f16x8*)(bhB_ + off_);                               \
            }                                                                         \
            _Pragma("unroll")                                                         \
            for (int m_ = 0; m_ < 4; ++m_)                                            \
                _Pragma("unroll")                                                     \
                for (int n_ = 0; n_ < 4; ++n_)                                        \
                    acc[m_][n_] = __builtin_amdgcn_mfma_f32_16x16x32_f16(             \
                        a_h[m_], b_h[n_], acc[m_][n_], 0, 0, 0);                      \
        }                                                                             \
    }

    STAGE_TILE(0, 0);
    STAGE_TILE(64, 1);

    for (int t = 0; t < 31; ++t) {
        asm volatile("s_waitcnt vmcnt(8)" ::: "memory");
        __builtin_amdgcn_s_barrier();
        COMPUTE_TILE(t & 1);
        __builtin_amdgcn_s_barrier();
        if (t < 30) STAGE_TILE((t + 2) * 64, t & 1);
    }
    asm volatile("s_waitcnt vmcnt(0)" ::: "memory");
    __builtin_amdgcn_s_barrier();
    COMPUTE_TILE(1);

#undef STAGE_TILE
#undef COMPUTE_TILE

    float mv[4][4]; int mi[4][4];
#pragma unroll
    for (int m = 0; m < 4; ++m)
#pragma unroll
        for (int r = 0; r < 4; ++r) { mv[m][r] = FLT_MAX; mi[m][r] = 0x7fffffff; }
#pragma unroll
    for (int n = 0; n < 4; ++n) {
        int c = colBase + wc * 64 + n * 16 + fr;
        float gq = gsq[c];
#pragma unroll
        for (int m = 0; m < 4; ++m)
#pragma unroll
            for (int r = 0; r < 4; ++r) {
                float d = gq - 2.0f * acc[m][n][r];
                if (d < mv[m][r]) { mv[m][r] = d; mi[m][r] = c; }
            }
    }
#pragma unroll
    for (int off = 1; off < 16; off <<= 1) {
#pragma unroll
        for (int m = 0; m < 4; ++m)
#pragma unroll
            for (int r = 0; r < 4; ++r) {
                float ov = __shfl_xor(mv[m][r], off);
                int   oi = __shfl_xor(mi[m][r], off);
                if (ov < mv[m][r] || (ov == mv[m][r] && oi < mi[m][r])) { mv[m][r] = ov; mi[m][r] = oi; }
            }
    }
    if (fr == 0) {
        const size_t slot = (size_t)(col * 2 + wc) * BSZ;
#pragma unroll
        for (int m = 0; m < 4; ++m)
#pragma unroll
            for (int r = 0; r < 4; ++r) {
                int grow = rowBase + wr * 64 + m * 16 + kg * 4 + r;
                pval[slot + grow] = mv[m][r];
                pidx[slot + grow] = mi[m][r];
            }
    }
}

// ---------------- K2b: fallback GEMM (in-loop q cvt, r17 -- measured 145us) ---------
__launch_bounds__(256)
__global__ void k_dist_r17(const float* __restrict__ q, const _Float16* __restrict__ gh,
                           const float* __restrict__ gsq,
                           float* __restrict__ pval, int* __restrict__ pidx) {
    __shared__ _Float16 ah[128][64];
    __shared__ _Float16 bh[128][64];

    const int tid = threadIdx.x;
    const int lane = tid & 63, wid = tid >> 6;
    const int wr = wid >> 1, wc = wid & 1;
    const int n0 = blockIdx.x;
    const int xcd = n0 & 7, j = n0 >> 3;
    const int col = j & 7, rowt = xcd * 16 + (j >> 3);
    const int colBase = col * 128, rowBase = rowt * 128;
    const int fr = lane & 15, kg = lane >> 4;

    char* ahB = (char*)&ah[0][0];
    const char* bhB = (const char*)&bh[0][0];

    f32x4 acc[4][4];
#pragma unroll
    for (int m = 0; m < 4; ++m)
#pragma unroll
        for (int n = 0; n < 4; ++n) acc[m][n] = (f32x4)0.f;

    for (int kb = 0; kb < QD; kb += 64) {
        __syncthreads();
#pragma unroll
        for (int s = 0; s < 8; ++s) {
            int f = s * 256 + tid;
            int row = f >> 4, k4 = (f & 15) * 4;
            float4 t = *(const float4*)(q + (size_t)(rowBase + row) * QD + kb + k4);
            f16x4 h;
            h[0] = (_Float16)t.x; h[1] = (_Float16)t.y;
            h[2] = (_Float16)t.z; h[3] = (_Float16)t.w;
            int byt = (row * 128 + k4 * 2) ^ ((row & 7) << 4);
            *(f16x4*)(ahB + byt) = h;
        }
#pragma unroll
        for (int i = 0; i < 4; ++i) {
            int g = wid * 4 + i;
            int row = g * 8 + (lane >> 3);
            int gran = (lane & 7) ^ (lane >> 3);
            size_t goff = (size_t)(colBase + row) * QD + kb + gran * 8;
            async_copy16(gh + goff, &bh[g * 8][0]);
        }
        __syncthreads();

#pragma unroll
        for (int h = 0; h < 2; ++h) {
            f16x8 a_h[4], b_h[4];
#pragma unroll
            for (int m = 0; m < 4; ++m) {
                int ar = wr * 64 + m * 16 + fr;
                int off = ar * 128 + ((h * 64 + kg * 16) ^ ((ar & 7) << 4));
                a_h[m] = *(const f16x8*)(ahB + off);
            }
#pragma unroll
            for (int n = 0; n < 4; ++n) {
                int br = wc * 64 + n * 16 + fr;
                int off = br * 128 + ((h * 64 + kg * 16) ^ ((br & 7) << 4));
                b_h[n] = *(const f16x8*)(bhB + off);
            }
#pragma unroll
            for (int m = 0; m < 4; ++m)
#pragma unroll
                for (int n = 0; n < 4; ++n)
                    acc[m][n] = __builtin_amdgcn_mfma_f32_16x16x32_f16(a_h[m], b_h[n], acc[m][n], 0, 0, 0);
        }
    }

    float mv[4][4]; int mi[4][4];
#pragma unroll
    for (int m = 0; m < 4; ++m)
#pragma unroll
        for (int r = 0; r < 4; ++r) { mv[m][r] = FLT_MAX; mi[m][r] = 0x7fffffff; }
#pragma unroll
    for (int n = 0; n < 4; ++n) {
        int c = colBase + wc * 64 + n * 16 + fr;
        float gq = gsq[c];
#pragma unroll
        for (int m = 0; m < 4; ++m)
#pragma unroll
            for (int r = 0; r < 4; ++r) {
                float d = gq - 2.0f * acc[m][n][r];
                if (d < mv[m][r]) { mv[m][r] = d; mi[m][r] = c; }
            }
    }
#pragma unroll
    for (int off = 1; off < 16; off <<= 1) {
#pragma unroll
        for (int m = 0; m < 4; ++m)
#pragma unroll
            for (int r = 0; r < 4; ++r) {
                float ov = __shfl_xor(mv[m][r], off);
                int   oi = __shfl_xor(mi[m][r], off);
                if (ov < mv[m][r] || (ov == mv[m][r] && oi < mi[m][r])) { mv[m][r] = ov; mi[m][r] = oi; }
            }
    }
    if (fr == 0) {
        const size_t slot = (size_t)(col * 2 + wc) * BSZ;
#pragma unroll
        for (int m = 0; m < 4; ++m)
#pragma unroll
            for (int r = 0; r < 4; ++r) {
                int grow = rowBase + wr * 64 + m * 16 + kg * 4 + r;
                pval[slot + grow] = mv[m][r];
                pidx[slot + grow] = mi[m][r];
            }
    }
}

// ---------------- K3: merge 16 partials -> argmin + fused qld + fused chunk-hist ----
__global__ void k_merge(const float* __restrict__ pval, const int* __restrict__ pidx,
                        const float* __restrict__ qsq,
                        int* __restrict__ idx_out, float* __restrict__ qld,
                        int* __restrict__ chunkhist) {
    __shared__ int h[NCODES];
    int c = blockIdx.x, tid = threadIdx.x;
    int b = c * 256 + tid;
#pragma unroll
    for (int s = 0; s < 4; ++s) h[tid + s * 256] = 0;
    float bv = pval[b]; int bi = pidx[b];
    for (int y = 1; y < NCOLG; ++y) {
        float v = pval[(size_t)y * BSZ + b]; int ii = pidx[(size_t)y * BSZ + b];
        if (v < bv || (v == bv && ii < bi)) { bv = v; bi = ii; }
    }
    idx_out[b] = bi;
    qld[b] = (qsq[b] + bv) * (1.0f / (float)QD);
    __syncthreads();
    atomicAdd(&h[bi], 1);
    __syncthreads();
#pragma unroll
    for (int s = 0; s < 4; ++s) chunkhist[c * NCODES + tid + s * 256] = h[tid + s * 256];
}

// ---------------- K4: scan (counting sort) + fused ec ----------------
__global__ void k_scan(const int* __restrict__ chunkhist, int* __restrict__ base,
                       int* __restrict__ counts, int* __restrict__ offsets,
                       const float* __restrict__ ema_count, float* __restrict__ ec_out) {
    __shared__ int s[NCODES];
    __shared__ float e2[NCODES];
    int code = threadIdx.x;  // 1024 threads
    int run = 0;
    for (int c = 0; c < NCHUNK; ++c) {
        base[c * NCODES + code] = run;
        run += chunkhist[c * NCODES + code];
    }
    counts[code] = run;
    s[code] = run; __syncthreads();
    for (int off = 1; off < NCODES; off <<= 1) {
        int v = (code >= off) ? s[code - off] : 0;
        __syncthreads();
        s[code] += v; __syncthreads();
    }
    offsets[code] = s[code] - run;
    float er = 0.99f * ema_count[code] + one_minus_decay() * (float)run;
    e2[code] = er; __syncthreads();
    for (int off = 512; off > 0; off >>= 1) {
        if (code < off) e2[code] += e2[code + off];
        __syncthreads();
    }
    float n = e2[0];
    ec_out[code] = (er + 1e-5f) / (n + (float)(2048.0 * 1e-5)) * n;
}

__global__ void k_fill(const int* __restrict__ idx, const int* __restrict__ base,
                       const int* __restrict__ offsets, int* __restrict__ list) {
    __shared__ int sidx[256];
    int c = blockIdx.x, tid = threadIdx.x;
    int b = c * 256 + tid;
    int n = idx[b];
    sidx[tid] = n; __syncthreads();
    int rank = 0;
    for (int j = 0; j < tid; ++j) rank += (sidx[j] == n);
    list[offsets[n] + base[c * NCODES + n] + rank] = b;
}

// ---------------- K6a: q_hat segment-sum (fp16 qh) + FUSED finalize ----------------
__global__ void k_qhat_fin_h(const _Float16* __restrict__ qh, const int* __restrict__ counts,
                             const int* __restrict__ offsets, const int* __restrict__ list,
                             const float* __restrict__ ema_dw, const float* __restrict__ ec,
                             float* __restrict__ edw_out, float* __restrict__ ctxnew_out,
                             float* __restrict__ outctx_out) {
    int n = blockIdx.x;
    int col = blockIdx.y * 256 + threadIdx.x;
    int cnt = counts[n];
    const int* lp = list + offsets[n];
    float a0 = 0.f, a1 = 0.f, a2 = 0.f, a3 = 0.f, a4 = 0.f, a5 = 0.f, a6 = 0.f, a7 = 0.f;
    int i = 0;
    for (; i + 8 <= cnt; i += 8) {
        int b0 = lp[i], b1 = lp[i + 1], b2 = lp[i + 2], b3 = lp[i + 3];
        int b4 = lp[i + 4], b5 = lp[i + 5], b6 = lp[i + 6], b7 = lp[i + 7];
        a0 += (float)qh[(size_t)b0 * QD + col]; a1 += (float)qh[(size_t)b1 * QD + col];
        a2 += (float)qh[(size_t)b2 * QD + col]; a3 += (float)qh[(size_t)b3 * QD + col];
        a4 += (float)qh[(size_t)b4 * QD + col]; a5 += (float)qh[(size_t)b5 * QD + col];
        a6 += (float)qh[(size_t)b6 * QD + col]; a7 += (float)qh[(size_t)b7 * QD + col];
    }
    for (; i < cnt; ++i) a0 += (float)qh[(size_t)lp[i] * QD + col];
    float r = ((a0 + a1) + (a2 + a3)) + ((a4 + a5) + (a6 + a7));
    size_t o = (size_t)n * QD + col;
    float ed = 0.99f * ema_dw[o] + one_minus_decay() * r;
    float cn = ed / ec[n];
    edw_out[o] = ed;
    ctxnew_out[o] = cn;
    outctx_out[o] = cn;
}

// ---------------- K6b: fallback (fp32 q) + fused finalize ----------------
__global__ void k_qhat_fin_f(const float* __restrict__ q, const int* __restrict__ counts,
                             const int* __restrict__ offsets, const int* __restrict__ list,
                             const float* __restrict__ ema_dw, const float* __restrict__ ec,
                             float* __restrict__ edw_out, float* __restrict__ ctxnew_out,
                             float* __restrict__ outctx_out) {
    int n = blockIdx.x;
    int col = blockIdx.y * 256 + threadIdx.x;
    int cnt = counts[n];
    const int* lp = list + offsets[n];
    float a0 = 0.f, a1 = 0.f, a2 = 0.f, a3 = 0.f, a4 = 0.f, a5 = 0.f, a6 = 0.f, a7 = 0.f;
    int i = 0;
    for (; i + 8 <= cnt; i += 8) {
        int b0 = lp[i], b1 = lp[i + 1], b2 = lp[i + 2], b3 = lp[i + 3];
        int b4 = lp[i + 4], b5 = lp[i + 5], b6 = lp[i + 6], b7 = lp[i + 7];
        a0 += q[(size_t)b0 * QD + col]; a1 += q[(size_t)b1 * QD + col];
        a2 += q[(size_t)b2 * QD + col]; a3 += q[(size_t)b3 * QD + col];
        a4 += q[(size_t)b4 * QD + col]; a5 += q[(size_t)b5 * QD + col];
        a6 += q[(size_t)b6 * QD + col]; a7 += q[(size_t)b7 * QD + col];
    }
    for (; i < cnt; ++i) a0 += q[(size_t)lp[i] * QD + col];
    float r = ((a0 + a1) + (a2 + a3)) + ((a4 + a5) + (a6 + a7));
    size_t o = (size_t)n * QD + col;
    float ed = 0.99f * ema_dw[o] + one_minus_decay() * r;
    float cn = ed / ec[n];
    edw_out[o] = ed;
    ctxnew_out[o] = cn;
    outctx_out[o] = cn;
}

extern "C" void kernel_launch(void* const* d_in, const int* in_sizes, int n_in,
                              void* d_out, int out_size, void* d_ws, size_t ws_size,
                              hipStream_t stream) {
    const float* q         = (const float*)d_in[0];
    const float* ctx       = (const float*)d_in[1];
    const float* ema_count = (const float*)d_in[2];
    const float* ema_dw    = (const float*)d_in[3];

    float* out = (float*)d_out;
    float* o_qld    = out;                              // 16384
    float* o_outctx = out + BSZ;                        // 2097152
    float* o_ec     = o_outctx + (size_t)NCODES * QD;   // 1024
    float* o_edw    = o_ec + NCODES;                    // 2097152
    float* o_ctxnew = o_edw + (size_t)NCODES * QD;      // 2097152

    char* w = (char*)d_ws;
    float* ws_gsq   = (float*)w;                        // 1024 f
    int* ws_idx     = (int*)(w + 4096);                 // 16384 i
    int* ws_counts  = (int*)(w + 4096 + 65536);         // 1024 i
    int* ws_offsets = ws_counts + NCODES;               // 1024 i
    int* ws_list    = ws_offsets + NCODES;              // 16384 i

    // qh pre-split scratch (64 MB) at ws + 1MB, if available
    const size_t presplit_need = (size_t)1048576 + (size_t)BSZ * QD * sizeof(_Float16);
    const bool use_pre = (ws_size >= presplit_need);
    _Float16* qh = (_Float16*)(w + 1048576);

    // scratch carved from not-yet-written d_out regions:
    _Float16* gh = (_Float16*)o_ctxnew;                 // 4MB (dead after k_dist)
    float* pval  = o_edw;                               // 1MB (dead after k_merge)
    int*   pidx  = (int*)(o_edw + (size_t)NCOLG * BSZ); // 1MB
    float* qsq   = o_edw + (size_t)2 * NCOLG * BSZ;     // 64KB (dead after k_merge)
    int* chunkhist = (int*)o_outctx;                    // 256KB (dead after k_scan)
    int* basep     = chunkhist + NCHUNK * NCODES;       // 256KB (dead after k_fill)

    if (use_pre) {
        k_prep_all<<<NCODES + BSZ, 256, 0, stream>>>(ctx, q, gh, ws_gsq, qh, qsq);
        k_dist_pre<<<1024, 256, 0, stream>>>(qh, gh, ws_gsq, pval, pidx);
    } else {
        k_prep_r17<<<NCODES + BSZ / 4, 256, 0, stream>>>(ctx, q, gh, ws_gsq, qsq);
        k_dist_r17<<<1024, 256, 0, stream>>>(q, gh, ws_gsq, pval, pidx);
    }
    k_merge <<<NCHUNK, 256, 0, stream>>>(pval, pidx, qsq, ws_idx, o_qld, chunkhist);
    k_scan  <<<1, 1024, 0, stream>>>(chunkhist, basep, ws_counts, ws_offsets, ema_count, o_ec);
    k_fill  <<<NCHUNK, 256, 0, stream>>>(ws_idx, basep, ws_offsets, ws_list);
    if (use_pre) {
        k_qhat_fin_h<<<dim3(NCODES, 8), 256, 0, stream>>>(qh, ws_counts, ws_offsets, ws_list,
                                                          ema_dw, o_ec, o_edw, o_ctxnew, o_outctx);
    } else {
        k_qhat_fin_f<<<dim3(NCODES, 8), 256, 0, stream>>>(q, ws_counts, ws_offsets, ws_list,
                                                          ema_dw, o_ec, o_edw, o_ctxnew, o_outctx);
    }
}